// Round 9
// baseline (818.490 us; speedup 1.0000x reference)
//
#include <hip/hip_runtime.h>
#include <hip/hip_bf16.h>

typedef __attribute__((ext_vector_type(8))) short short8;
typedef __attribute__((ext_vector_type(4))) float f32x4;

#define N_PROP 512
#define DHID   1024
#define KFLAT  50176
#define SM_SCALE 0.03125f  /* 1/sqrt(1024) */

__device__ inline short f2bf(float x) {
  __hip_bfloat16 b = __float2bfloat16(x);
  return __builtin_bit_cast(short, b);
}

// Raw barrier WITHOUT the compiler's vmcnt(0) drain: lgkmcnt(0) orders LDS
// writes/reads across the barrier; global loads stay in flight.
__device__ inline void pinned_bar() {
  asm volatile("s_waitcnt lgkmcnt(0)" ::: "memory");
  __builtin_amdgcn_s_barrier();
  asm volatile("" ::: "memory");
}

// ---------------- fc1: UNCHANGED from round 8 (at its memory-fill roofline:
// 822 MB requested at ~6.1 TB/s aggregate = measured 129 us; conflicts 0) ----
__global__ __launch_bounds__(1024, 4)
void gemm_fc1(const float* __restrict__ A, const float* __restrict__ B,
              __hip_bfloat16* __restrict__ parts)
{
  constexpr int BK = 32;
  constexpr int KLEN = 1568, NT = KLEN / BK;   // 49
  __shared__ short sA[2][256 * 32];
  __shared__ short sB[2][256 * 32];            // 64 KB total

  const int n = gridDim.x;
  int lid = blockIdx.x;
  lid = (lid & 7) * (n >> 3) + (lid >> 3);
  const int y    = lid >> 3;
  const int tile = lid & 7;
  const int tm = tile >> 2;
  const int tn = tile & 3;

  const int k0 = y * KLEN;

  const int tid  = threadIdx.x;
  const int lane = tid & 63;
  const int wid  = tid >> 6;
  const int wr = wid >> 2, wc = wid & 3;
  const int l16 = lane & 15, kq = lane >> 4;

  const float* Ab = A + (size_t)(tm * 256) * KFLAT;
  const float* Bb = B + (size_t)(tn * 256) * KFLAT;

  const int srow = tid >> 2;
  const int sc   = tid & 3;
  const int sphys = sc ^ ((srow >> 1) & 3);

  f32x4 acc[4][4];
  #pragma unroll
  for (int i = 0; i < 4; ++i)
    #pragma unroll
    for (int j = 0; j < 4; ++j)
      acc[i][j] = (f32x4){0.f, 0.f, 0.f, 0.f};

  float4 ra0, ra1, rb0, rb1;

  auto loadAB = [&](int kk) {
    const float* pa = Ab + (size_t)srow * KFLAT + kk + sc * 8;
    const float* pb = Bb + (size_t)srow * KFLAT + kk + sc * 8;
    ra0 = *(const float4*)pa; ra1 = *(const float4*)(pa + 4);
    rb0 = *(const float4*)pb; rb1 = *(const float4*)(pb + 4);
  };
  auto storeAB = [&](int b) {
    short8 s;
    s[0]=f2bf(ra0.x); s[1]=f2bf(ra0.y); s[2]=f2bf(ra0.z); s[3]=f2bf(ra0.w);
    s[4]=f2bf(ra1.x); s[5]=f2bf(ra1.y); s[6]=f2bf(ra1.z); s[7]=f2bf(ra1.w);
    *(short8*)&sA[b][srow * 32 + sphys * 8] = s;
    s[0]=f2bf(rb0.x); s[1]=f2bf(rb0.y); s[2]=f2bf(rb0.z); s[3]=f2bf(rb0.w);
    s[4]=f2bf(rb1.x); s[5]=f2bf(rb1.y); s[6]=f2bf(rb1.z); s[7]=f2bf(rb1.w);
    *(short8*)&sB[b][srow * 32 + sphys * 8] = s;
  };
  auto compute = [&](int b) {
    short8 af[4], bf[4];
    #pragma unroll
    for (int i = 0; i < 4; ++i) {
      int R  = wr * 64 + i * 16 + l16;
      int ph = kq ^ ((R >> 1) & 3);
      af[i] = *(short8*)&sA[b][R * 32 + ph * 8];
    }
    #pragma unroll
    for (int j = 0; j < 4; ++j) {
      int R  = wc * 64 + j * 16 + l16;
      int ph = kq ^ ((R >> 1) & 3);
      bf[j] = *(short8*)&sB[b][R * 32 + ph * 8];
    }
    #pragma unroll
    for (int i = 0; i < 4; ++i)
      #pragma unroll
      for (int j = 0; j < 4; ++j)
        acc[i][j] = __builtin_amdgcn_mfma_f32_16x16x32_bf16(af[i], bf[j], acc[i][j], 0, 0, 0);
  };

  loadAB(k0);
  storeAB(0);
  loadAB(k0 + BK);
  pinned_bar();

  int cur = 0;
  for (int t = 0; t < NT; ++t) {
    if (t + 1 < NT) {
      storeAB(cur ^ 1);
      if (t + 2 < NT) loadAB(k0 + (t + 2) * BK);
    }
    compute(cur);
    pinned_bar();
    cur ^= 1;
  }

  __hip_bfloat16* P = parts + (size_t)y * (N_PROP * DHID);
  const int crow0 = tm * 256 + wr * 64;
  const int ccol0 = tn * 256 + wc * 64;
  #pragma unroll
  for (int i = 0; i < 4; ++i)
    #pragma unroll
    for (int j = 0; j < 4; ++j)
      #pragma unroll
      for (int e = 0; e < 4; ++e) {
        int r = crow0 + i * 16 + kq * 4 + e;
        int c = ccol0 + j * 16 + l16;
        P[(size_t)r * DHID + c] = __float2bfloat16(acc[i][j][e]);
      }
}

// ---------------- tail GEMM: bf16 A, B either fp32 (weights) or bf16 --------
// dbuf LDS + ONE pinned_bar per K-step + 2-deep ping-pong reg prefetch.
// Epilogue: +bias(fp32) +res1 +res2 (fp32), relu, writes C(fp32) and/or
// Cb(bf16) and/or Ct(bf16 transpose).
template<int BM, int BN, int BK, typename BT>
__global__ __launch_bounds__(256, 2)
void gemm_bf(const __hip_bfloat16* __restrict__ A, int lda,
             const BT* __restrict__ B1, const BT* __restrict__ B2, int ldb,
             float* __restrict__ C, __hip_bfloat16* __restrict__ Cb, int ldc,
             int tiles_n, int ktot, size_t c_z_stride,
             const float* __restrict__ bias1, const float* __restrict__ bias2,
             const float* __restrict__ res1, const float* __restrict__ res2,
             __hip_bfloat16* __restrict__ Ct, int ldct, int do_relu)
{
  constexpr int BKP = BK + 8;
  constexpr int WM = BM / 2, WN = BN / 2;
  constexpr int FM = WM / 16, FN = WN / 16;
  constexpr int NC = BK / 8;                  // short8 chunks per LDS row
  constexpr int NA = (BM * BK) / (8 * 256);
  constexpr int NB = (BN * BK) / (8 * 256);
  constexpr bool BF = sizeof(BT) == 2;

  __shared__ short As[2][BM * BKP];
  __shared__ short Bs[2][BN * BKP];

  const int n = gridDim.x;
  int lid = blockIdx.x;
  lid = (lid & 7) * (n >> 3) + (lid >> 3);
  const int tm = lid / tiles_n;
  const int tn = lid % tiles_n;
  const int nt = ktot / BK;

  if (C)  C  += (size_t)blockIdx.z * c_z_stride;
  if (Cb) Cb += (size_t)blockIdx.z * c_z_stride;
  const BT* B      = blockIdx.z ? B2 : B1;
  const float* bias = blockIdx.z ? bias2 : bias1;

  const int tid  = threadIdx.x;
  const int lane = tid & 63;
  const int wid  = tid >> 6;
  const int wm = wid >> 1, wn = wid & 1;
  const int l16 = lane & 15, kq = lane >> 4;

  const __hip_bfloat16* Ab = A + (size_t)(tm * BM) * lda;
  const BT*             Bb = B + (size_t)(tn * BN) * ldb;

  f32x4 acc[FM][FN];
  #pragma unroll
  for (int i = 0; i < FM; ++i)
    #pragma unroll
    for (int j = 0; j < FN; ++j)
      acc[i][j] = (f32x4){0.f, 0.f, 0.f, 0.f};

  short8 rah[2][NA];          // A is always bf16
  short8 rbh[2][NB];          // used when BT==bf16
  float4 rbf[2][NB][2];       // used when BT==float

  auto loadAB = [&](int kk, int s) {
    #pragma unroll
    for (int i = 0; i < NA; ++i) {
      int ch = tid + i * 256;
      int r = ch / NC, c = (ch % NC) * 8;
      rah[s][i] = *(const short8*)(Ab + (size_t)r * lda + kk + c);
    }
    #pragma unroll
    for (int i = 0; i < NB; ++i) {
      int ch = tid + i * 256;
      int r = ch / NC, c = (ch % NC) * 8;
      if constexpr (BF) {
        rbh[s][i] = *(const short8*)(Bb + (size_t)r * ldb + kk + c);
      } else {
        const float* p = (const float*)Bb + (size_t)r * ldb + kk + c;
        rbf[s][i][0] = *(const float4*)p;
        rbf[s][i][1] = *(const float4*)(p + 4);
      }
    }
  };
  auto storeAB = [&](int s, int b) {
    #pragma unroll
    for (int i = 0; i < NA; ++i) {
      int ch = tid + i * 256;
      int r = ch / NC, c = (ch % NC) * 8;
      *(short8*)&As[b][r * BKP + c] = rah[s][i];
    }
    #pragma unroll
    for (int i = 0; i < NB; ++i) {
      int ch = tid + i * 256;
      int r = ch / NC, c = (ch % NC) * 8;
      if constexpr (BF) {
        *(short8*)&Bs[b][r * BKP + c] = rbh[s][i];
      } else {
        float4 u = rbf[s][i][0], v = rbf[s][i][1];
        short8 w;
        w[0]=f2bf(u.x); w[1]=f2bf(u.y); w[2]=f2bf(u.z); w[3]=f2bf(u.w);
        w[4]=f2bf(v.x); w[5]=f2bf(v.y); w[6]=f2bf(v.z); w[7]=f2bf(v.w);
        *(short8*)&Bs[b][r * BKP + c] = w;
      }
    }
  };
  auto compute = [&](int b) {
    #pragma unroll
    for (int ks = 0; ks < BK / 32; ++ks) {
      short8 af[FM], bf[FN];
      #pragma unroll
      for (int i = 0; i < FM; ++i)
        af[i] = *(short8*)&As[b][(wm * WM + i * 16 + l16) * BKP + ks * 32 + kq * 8];
      #pragma unroll
      for (int j = 0; j < FN; ++j)
        bf[j] = *(short8*)&Bs[b][(wn * WN + j * 16 + l16) * BKP + ks * 32 + kq * 8];
      #pragma unroll
      for (int i = 0; i < FM; ++i)
        #pragma unroll
        for (int j = 0; j < FN; ++j)
          acc[i][j] = __builtin_amdgcn_mfma_f32_16x16x32_bf16(af[i], bf[j], acc[i][j], 0, 0, 0);
    }
  };

  // prologue: tile0 -> set0 -> buf0; tile1 -> set1.
  loadAB(0, 0);
  storeAB(0, 0);
  loadAB(BK, 1);
  pinned_bar();

  int cur = 0;
  for (int t = 0; t < nt; ++t) {
    if (t + 1 < nt) storeAB((t + 1) & 1, cur ^ 1);
    if (t + 2 < nt) loadAB((t + 2) * BK, t & 1);
    compute(cur);
    pinned_bar();
    cur ^= 1;
  }

  const int crow0 = tm * BM + wm * WM;
  const int ccol0 = tn * BN + wn * WN;
  #pragma unroll
  for (int i = 0; i < FM; ++i)
    #pragma unroll
    for (int j = 0; j < FN; ++j)
      #pragma unroll
      for (int e = 0; e < 4; ++e) {
        int r = crow0 + i * 16 + kq * 4 + e;
        int c = ccol0 + j * 16 + l16;
        float v = acc[i][j][e];
        if (bias) v += bias[c];
        if (res1) v += res1[(size_t)r * ldc + c];
        if (res2) v += res2[(size_t)r * ldc + c];
        if (do_relu) v = fmaxf(v, 0.f);
        if (C)  C [(size_t)r * ldc + c] = v;
        if (Cb) Cb[(size_t)r * ldc + c] = __float2bfloat16(v);
        if (Ct) Ct[(size_t)c * ldct + r] = __float2bfloat16(v);
      }
}

// reduce partials + bias -> out0f (fp32), out0b (bf16), T = out0^T (bf16).
__global__ __launch_bounds__(256)
void reduce_t(const __hip_bfloat16* __restrict__ parts, const float* __restrict__ bias,
              float* __restrict__ out0f, __hip_bfloat16* __restrict__ out0b,
              __hip_bfloat16* __restrict__ T)
{
  __shared__ float tile[32][33];
  int bx = blockIdx.x * 32;          // col in DHID
  int by = blockIdx.y * 32;          // row in N_PROP
  int tx = threadIdx.x & 31, ty = threadIdx.x >> 5;   // 32 x 8
  #pragma unroll
  for (int i = 0; i < 4; ++i) {
    int r = by + ty + i * 8, c = bx + tx;
    float s = bias[c];
    for (int sl = 0; sl < 32; ++sl)
      s += __bfloat162float(parts[(size_t)sl * (N_PROP * DHID) + (size_t)r * DHID + c]);
    out0f[(size_t)r * DHID + c] = s;
    out0b[(size_t)r * DHID + c] = __float2bfloat16(s);
    tile[ty + i * 8][tx] = s;
  }
  __syncthreads();
  #pragma unroll
  for (int i = 0; i < 4; ++i)
    T[(size_t)(bx + ty + i * 8) * N_PROP + by + tx] =
        __float2bfloat16(tile[tx][ty + i * 8]);
}

// row softmax of logits[512][512] (fp32 in), bf16 probabilities out.
__global__ __launch_bounds__(256)
void softmax_rows(const float* __restrict__ x, __hip_bfloat16* __restrict__ p, float scale)
{
  int row = blockIdx.x;
  const float* q = x + (size_t)row * N_PROP;
  int tid = threadIdx.x;
  float a = q[tid] * scale;
  float b = q[tid + 256] * scale;
  float m = fmaxf(a, b);
  #pragma unroll
  for (int o = 32; o > 0; o >>= 1) m = fmaxf(m, __shfl_xor(m, o));
  __shared__ float sm[4], ss[4];
  int w = tid >> 6;
  if ((tid & 63) == 0) sm[w] = m;
  __syncthreads();
  m = fmaxf(fmaxf(sm[0], sm[1]), fmaxf(sm[2], sm[3]));
  float ea = __expf(a - m), eb = __expf(b - m);
  float s = ea + eb;
  #pragma unroll
  for (int o = 32; o > 0; o >>= 1) s += __shfl_xor(s, o);
  if ((tid & 63) == 0) ss[w] = s;
  __syncthreads();
  s = ss[0] + ss[1] + ss[2] + ss[3];
  float inv = 1.f / s;
  p[(size_t)row * N_PROP + tid]       = __float2bfloat16(ea * inv);
  p[(size_t)row * N_PROP + tid + 256] = __float2bfloat16(eb * inv);
}

extern "C" void kernel_launch(void* const* d_in, const int* in_sizes, int n_in,
                              void* d_out, int out_size, void* d_ws, size_t ws_size,
                              hipStream_t stream)
{
  (void)in_sizes; (void)n_in; (void)out_size; (void)ws_size;
  const float* x      = (const float*)d_in[0];
  const float* fc1_w  = (const float*)d_in[1];
  const float* fc1_b  = (const float*)d_in[2];
  const float* fc2_w  = (const float*)d_in[3];
  const float* fc2_b  = (const float*)d_in[4];
  const float* a1w1   = (const float*)d_in[5];
  const float* a1b1   = (const float*)d_in[6];
  const float* a1w2   = (const float*)d_in[7];
  const float* a1b2   = (const float*)d_in[8];
  const float* a1cw   = (const float*)d_in[9];
  const float* a1cb   = (const float*)d_in[10];
  const float* a2w1   = (const float*)d_in[11];
  const float* a2b1   = (const float*)d_in[12];
  const float* a2w2   = (const float*)d_in[13];
  const float* a2b2   = (const float*)d_in[14];
  const float* a2cw   = (const float*)d_in[15];
  const float* a2cb   = (const float*)d_in[16];
  float* out = (float*)d_out;

  typedef __hip_bfloat16 bf16;
  char* ws = (char*)d_ws;
  const size_t MB = 1024 * 1024;
  float* out0f  = (float*)(ws + 0 * MB);            // 2 MB
  float* h1f    = (float*)(ws + 2 * MB);            // 2 MB
  float* logits = (float*)(ws + 4 * MB);            // 1 MB (512x512 fp32)
  bf16*  out0b  = (bf16*)(ws + 5 * MB);             // 1 MB
  bf16*  T      = (bf16*)(ws + 6 * MB);             // 1 MB (out0^T, 1024x512)
  bf16*  q      = (bf16*)(ws + 7 * MB);             // 1 MB
  bf16*  k      = (bf16*)(ws + 8 * MB);             // 1 MB (adjacent to q: dual-z)
  bf16*  att    = (bf16*)(ws + 9 * MB);             // 1 MB
  bf16*  h0b    = (bf16*)(ws + 10 * MB);            // 1 MB
  bf16*  h1b    = (bf16*)(ws + 11 * MB);            // 1 MB
  bf16*  T2     = (bf16*)(ws + 12 * MB);            // 1 MB (h1^T)
  bf16*  pb     = (bf16*)(ws + 13 * MB);            // 0.5 MB
  bf16*  parts  = (bf16*)(ws + 14 * MB);            // 32 MB -> total 46 MB
  const size_t ND = (size_t)N_PROP * DHID;
  dim3 blk(256);

  // ---- fc1 (unchanged roofline kernel) + fused reduce/bias/transpose ----
  gemm_fc1<<<dim3(256), dim3(1024), 0, stream>>>(x, fc1_w, parts);
  reduce_t<<<dim3(DHID / 32, N_PROP / 32), blk, 0, stream>>>(
      parts, fc1_b, out0f, out0b, T);

  // ---- attention 1 ----
  gemm_bf<32, 64, 128, float><<<dim3(256, 1, 2), blk, 0, stream>>>(
      out0b, DHID, a1w1, a1w2, DHID,
      nullptr, q, DHID, 16, DHID, ND,
      a1b1, a1b2, nullptr, nullptr, nullptr, 0, 0);
  gemm_bf<32, 32, 128, bf16><<<dim3(256), blk, 0, stream>>>(
      q, DHID, k, nullptr, DHID,
      logits, nullptr, N_PROP, 16, DHID, 0,
      nullptr, nullptr, nullptr, nullptr, nullptr, 0, 0);
  softmax_rows<<<N_PROP, blk, 0, stream>>>(logits, pb, SM_SCALE);
  gemm_bf<32, 64, 128, bf16><<<dim3(256), blk, 0, stream>>>(
      pb, N_PROP, T, nullptr, N_PROP,
      nullptr, att, DHID, 16, N_PROP, 0,
      nullptr, nullptr, nullptr, nullptr, nullptr, 0, 0);
  // h0 = relu(out0 + att @ a1cw^T + a1cb)
  gemm_bf<32, 64, 128, float><<<dim3(256), blk, 0, stream>>>(
      att, DHID, a1cw, nullptr, DHID,
      nullptr, h0b, DHID, 16, DHID, 0,
      a1cb, nullptr, out0f, nullptr, nullptr, 0, 1);
  // h1 = h0 @ fc2^T + fc2_b ; emit h1f + h1b + T2 = h1^T
  gemm_bf<32, 64, 128, float><<<dim3(256), blk, 0, stream>>>(
      h0b, DHID, fc2_w, nullptr, DHID,
      h1f, h1b, DHID, 16, DHID, 0,
      fc2_b, nullptr, nullptr, nullptr, T2, N_PROP, 0);

  // ---- attention 2 ----
  gemm_bf<32, 64, 128, float><<<dim3(256, 1, 2), blk, 0, stream>>>(
      h1b, DHID, a2w1, a2w2, DHID,
      nullptr, q, DHID, 16, DHID, ND,
      a2b1, a2b2, nullptr, nullptr, nullptr, 0, 0);
  gemm_bf<32, 32, 128, bf16><<<dim3(256), blk, 0, stream>>>(
      q, DHID, k, nullptr, DHID,
      logits, nullptr, N_PROP, 16, DHID, 0,
      nullptr, nullptr, nullptr, nullptr, nullptr, 0, 0);
  softmax_rows<<<N_PROP, blk, 0, stream>>>(logits, pb, SM_SCALE);
  gemm_bf<32, 64, 128, bf16><<<dim3(256), blk, 0, stream>>>(
      pb, N_PROP, T2, nullptr, N_PROP,
      nullptr, att, DHID, 16, N_PROP, 0,
      nullptr, nullptr, nullptr, nullptr, nullptr, 0, 0);
  // final = relu(h1 + att @ a2cw^T + a2cb + out0)
  gemm_bf<32, 64, 128, float><<<dim3(256), blk, 0, stream>>>(
      att, DHID, a2cw, nullptr, DHID,
      out, nullptr, DHID, 16, DHID, 0,
      a2cb, nullptr, h1f, out0f, nullptr, 0, 1);
}

// Round 10
// 196.120 us; speedup vs baseline: 4.1734x; 4.1734x over previous
//
#include <hip/hip_runtime.h>
#include <hip/hip_bf16.h>

typedef __attribute__((ext_vector_type(8))) short short8;
typedef __attribute__((ext_vector_type(4))) float f32x4;

#define N_PROP 512
#define DHID   1024
#define KFLAT  50176
#define SM_SCALE 0.03125f  /* 1/sqrt(1024) */

__device__ inline short f2bf(float x) {
  __hip_bfloat16 b = __float2bfloat16(x);
  return __builtin_bit_cast(short, b);
}
__device__ inline float bf2f(unsigned short u) {
  unsigned int x = (unsigned int)u << 16;
  return __builtin_bit_cast(float, x);
}

// Raw barrier WITHOUT the compiler's vmcnt(0) drain: lgkmcnt(0) orders LDS
// writes/reads across the barrier; global loads stay in flight.
__device__ inline void pinned_bar() {
  asm volatile("s_waitcnt lgkmcnt(0)" ::: "memory");
  __builtin_amdgcn_s_barrier();
  asm volatile("" ::: "memory");
}

// ---------------- fc1: UNCHANGED (at its memory-fill roofline: 822 MB
// requested at ~6.1 TB/s aggregate = ~128 us; bank conflicts 0) -------------
__global__ __launch_bounds__(1024, 4)
void gemm_fc1(const float* __restrict__ A, const float* __restrict__ B,
              __hip_bfloat16* __restrict__ parts)
{
  constexpr int BK = 32;
  constexpr int KLEN = 1568, NT = KLEN / BK;   // 49
  __shared__ short sA[2][256 * 32];
  __shared__ short sB[2][256 * 32];            // 64 KB total

  const int n = gridDim.x;
  int lid = blockIdx.x;
  lid = (lid & 7) * (n >> 3) + (lid >> 3);
  const int y    = lid >> 3;
  const int tile = lid & 7;
  const int tm = tile >> 2;
  const int tn = tile & 3;

  const int k0 = y * KLEN;

  const int tid  = threadIdx.x;
  const int lane = tid & 63;
  const int wid  = tid >> 6;
  const int wr = wid >> 2, wc = wid & 3;
  const int l16 = lane & 15, kq = lane >> 4;

  const float* Ab = A + (size_t)(tm * 256) * KFLAT;
  const float* Bb = B + (size_t)(tn * 256) * KFLAT;

  const int srow = tid >> 2;
  const int sc   = tid & 3;
  const int sphys = sc ^ ((srow >> 1) & 3);

  f32x4 acc[4][4];
  #pragma unroll
  for (int i = 0; i < 4; ++i)
    #pragma unroll
    for (int j = 0; j < 4; ++j)
      acc[i][j] = (f32x4){0.f, 0.f, 0.f, 0.f};

  float4 ra0, ra1, rb0, rb1;

  auto loadAB = [&](int kk) {
    const float* pa = Ab + (size_t)srow * KFLAT + kk + sc * 8;
    const float* pb = Bb + (size_t)srow * KFLAT + kk + sc * 8;
    ra0 = *(const float4*)pa; ra1 = *(const float4*)(pa + 4);
    rb0 = *(const float4*)pb; rb1 = *(const float4*)(pb + 4);
  };
  auto storeAB = [&](int b) {
    short8 s;
    s[0]=f2bf(ra0.x); s[1]=f2bf(ra0.y); s[2]=f2bf(ra0.z); s[3]=f2bf(ra0.w);
    s[4]=f2bf(ra1.x); s[5]=f2bf(ra1.y); s[6]=f2bf(ra1.z); s[7]=f2bf(ra1.w);
    *(short8*)&sA[b][srow * 32 + sphys * 8] = s;
    s[0]=f2bf(rb0.x); s[1]=f2bf(rb0.y); s[2]=f2bf(rb0.z); s[3]=f2bf(rb0.w);
    s[4]=f2bf(rb1.x); s[5]=f2bf(rb1.y); s[6]=f2bf(rb1.z); s[7]=f2bf(rb1.w);
    *(short8*)&sB[b][srow * 32 + sphys * 8] = s;
  };
  auto compute = [&](int b) {
    short8 af[4], bf[4];
    #pragma unroll
    for (int i = 0; i < 4; ++i) {
      int R  = wr * 64 + i * 16 + l16;
      int ph = kq ^ ((R >> 1) & 3);
      af[i] = *(short8*)&sA[b][R * 32 + ph * 8];
    }
    #pragma unroll
    for (int j = 0; j < 4; ++j) {
      int R  = wc * 64 + j * 16 + l16;
      int ph = kq ^ ((R >> 1) & 3);
      bf[j] = *(short8*)&sB[b][R * 32 + ph * 8];
    }
    #pragma unroll
    for (int i = 0; i < 4; ++i)
      #pragma unroll
      for (int j = 0; j < 4; ++j)
        acc[i][j] = __builtin_amdgcn_mfma_f32_16x16x32_bf16(af[i], bf[j], acc[i][j], 0, 0, 0);
  };

  loadAB(k0);
  storeAB(0);
  loadAB(k0 + BK);
  pinned_bar();

  int cur = 0;
  for (int t = 0; t < NT; ++t) {
    if (t + 1 < NT) {
      storeAB(cur ^ 1);
      if (t + 2 < NT) loadAB(k0 + (t + 2) * BK);
    }
    compute(cur);
    pinned_bar();
    cur ^= 1;
  }

  __hip_bfloat16* P = parts + (size_t)y * (N_PROP * DHID);
  const int crow0 = tm * 256 + wr * 64;
  const int ccol0 = tn * 256 + wc * 64;
  #pragma unroll
  for (int i = 0; i < 4; ++i)
    #pragma unroll
    for (int j = 0; j < 4; ++j)
      #pragma unroll
      for (int e = 0; e < 4; ++e) {
        int r = crow0 + i * 16 + kq * 4 + e;
        int c = ccol0 + j * 16 + l16;
        P[(size_t)r * DHID + c] = __float2bfloat16(acc[i][j][e]);
      }
}

// ---------------- tail GEMM: bf16 A, B fp32 (weights) or bf16 ---------------
// dbuf LDS + ONE pinned_bar per K-step. Register staging sets are STATICALLY
// NAMED (set0/set1) and the loop is unrolled by 2 — rule #20: runtime-indexed
// register arrays go to scratch (round-9 regression: 92us tail -> 690us).
// nt is always even here (ktot/BK = 8 or 4).
template<int BM, int BN, int BK, typename BT>
__global__ __launch_bounds__(256, 2)
void gemm_bf(const __hip_bfloat16* __restrict__ A, int lda,
             const BT* __restrict__ B1, const BT* __restrict__ B2, int ldb,
             float* __restrict__ C, __hip_bfloat16* __restrict__ Cb, int ldc,
             int tiles_n, int ktot, size_t c_z_stride,
             const float* __restrict__ bias1, const float* __restrict__ bias2,
             const float* __restrict__ res1, const float* __restrict__ res2,
             __hip_bfloat16* __restrict__ Ct, int ldct, int do_relu)
{
  constexpr int BKP = BK + 8;
  constexpr int WM = BM / 2, WN = BN / 2;
  constexpr int FM = WM / 16, FN = WN / 16;
  constexpr int NC = BK / 8;
  constexpr int NA = (BM * BK) / (8 * 256);
  constexpr int NB = (BN * BK) / (8 * 256);
  constexpr bool BF = sizeof(BT) == 2;

  __shared__ short As[2][BM * BKP];
  __shared__ short Bs[2][BN * BKP];

  const int n = gridDim.x;
  int lid = blockIdx.x;
  lid = (lid & 7) * (n >> 3) + (lid >> 3);
  const int tm = lid / tiles_n;
  const int tn = lid % tiles_n;
  const int nt = ktot / BK;

  if (C)  C  += (size_t)blockIdx.z * c_z_stride;
  if (Cb) Cb += (size_t)blockIdx.z * c_z_stride;
  const BT* B       = blockIdx.z ? B2 : B1;
  const float* bias = blockIdx.z ? bias2 : bias1;

  const int tid  = threadIdx.x;
  const int lane = tid & 63;
  const int wid  = tid >> 6;
  const int wm = wid >> 1, wn = wid & 1;
  const int l16 = lane & 15, kq = lane >> 4;

  const __hip_bfloat16* Ab = A + (size_t)(tm * BM) * lda;
  const BT*             Bb = B + (size_t)(tn * BN) * ldb;

  f32x4 acc[FM][FN];
  #pragma unroll
  for (int i = 0; i < FM; ++i)
    #pragma unroll
    for (int j = 0; j < FN; ++j)
      acc[i][j] = (f32x4){0.f, 0.f, 0.f, 0.f};

  // set 0 (statically named)
  short8 a0[NA]; short8 b0h[NB]; float4 b0f[NB][2];
  // set 1 (statically named)
  short8 a1[NA]; short8 b1h[NB]; float4 b1f[NB][2];

  auto load0 = [&](int kk) {
    #pragma unroll
    for (int i = 0; i < NA; ++i) {
      int ch = tid + i * 256; int r = ch / NC, c = (ch % NC) * 8;
      a0[i] = *(const short8*)(Ab + (size_t)r * lda + kk + c);
    }
    #pragma unroll
    for (int i = 0; i < NB; ++i) {
      int ch = tid + i * 256; int r = ch / NC, c = (ch % NC) * 8;
      if constexpr (BF) b0h[i] = *(const short8*)(Bb + (size_t)r * ldb + kk + c);
      else {
        const float* p = (const float*)Bb + (size_t)r * ldb + kk + c;
        b0f[i][0] = *(const float4*)p; b0f[i][1] = *(const float4*)(p + 4);
      }
    }
  };
  auto load1 = [&](int kk) {
    #pragma unroll
    for (int i = 0; i < NA; ++i) {
      int ch = tid + i * 256; int r = ch / NC, c = (ch % NC) * 8;
      a1[i] = *(const short8*)(Ab + (size_t)r * lda + kk + c);
    }
    #pragma unroll
    for (int i = 0; i < NB; ++i) {
      int ch = tid + i * 256; int r = ch / NC, c = (ch % NC) * 8;
      if constexpr (BF) b1h[i] = *(const short8*)(Bb + (size_t)r * ldb + kk + c);
      else {
        const float* p = (const float*)Bb + (size_t)r * ldb + kk + c;
        b1f[i][0] = *(const float4*)p; b1f[i][1] = *(const float4*)(p + 4);
      }
    }
  };
  auto store0 = [&](int buf) {
    #pragma unroll
    for (int i = 0; i < NA; ++i) {
      int ch = tid + i * 256; int r = ch / NC, c = (ch % NC) * 8;
      *(short8*)&As[buf][r * BKP + c] = a0[i];
    }
    #pragma unroll
    for (int i = 0; i < NB; ++i) {
      int ch = tid + i * 256; int r = ch / NC, c = (ch % NC) * 8;
      if constexpr (BF) *(short8*)&Bs[buf][r * BKP + c] = b0h[i];
      else {
        float4 u = b0f[i][0], v = b0f[i][1];
        short8 w;
        w[0]=f2bf(u.x); w[1]=f2bf(u.y); w[2]=f2bf(u.z); w[3]=f2bf(u.w);
        w[4]=f2bf(v.x); w[5]=f2bf(v.y); w[6]=f2bf(v.z); w[7]=f2bf(v.w);
        *(short8*)&Bs[buf][r * BKP + c] = w;
      }
    }
  };
  auto store1 = [&](int buf) {
    #pragma unroll
    for (int i = 0; i < NA; ++i) {
      int ch = tid + i * 256; int r = ch / NC, c = (ch % NC) * 8;
      *(short8*)&As[buf][r * BKP + c] = a1[i];
    }
    #pragma unroll
    for (int i = 0; i < NB; ++i) {
      int ch = tid + i * 256; int r = ch / NC, c = (ch % NC) * 8;
      if constexpr (BF) *(short8*)&Bs[buf][r * BKP + c] = b1h[i];
      else {
        float4 u = b1f[i][0], v = b1f[i][1];
        short8 w;
        w[0]=f2bf(u.x); w[1]=f2bf(u.y); w[2]=f2bf(u.z); w[3]=f2bf(u.w);
        w[4]=f2bf(v.x); w[5]=f2bf(v.y); w[6]=f2bf(v.z); w[7]=f2bf(v.w);
        *(short8*)&Bs[buf][r * BKP + c] = w;
      }
    }
  };
  auto compute = [&](int buf) {
    #pragma unroll
    for (int ks = 0; ks < BK / 32; ++ks) {
      short8 af[FM], bf[FN];
      #pragma unroll
      for (int i = 0; i < FM; ++i)
        af[i] = *(short8*)&As[buf][(wm * WM + i * 16 + l16) * BKP + ks * 32 + kq * 8];
      #pragma unroll
      for (int j = 0; j < FN; ++j)
        bf[j] = *(short8*)&Bs[buf][(wn * WN + j * 16 + l16) * BKP + ks * 32 + kq * 8];
      #pragma unroll
      for (int i = 0; i < FM; ++i)
        #pragma unroll
        for (int j = 0; j < FN; ++j)
          acc[i][j] = __builtin_amdgcn_mfma_f32_16x16x32_bf16(af[i], bf[j], acc[i][j], 0, 0, 0);
    }
  };

  // prologue: tile0 -> set0 -> buf0; tile1 -> set1 (regs only).
  load0(0);
  store0(0);
  load1(BK);
  pinned_bar();

  int t = 0;
  for (; t + 2 < nt; t += 2) {
    store1(1); load0((t + 2) * BK);
    compute(0); pinned_bar();
    store0(0); load1((t + 3) * BK);
    compute(1); pinned_bar();
  }
  // epilogue pair: set1 holds tile nt-1; buf0 holds tile nt-2.
  store1(1);
  compute(0); pinned_bar();
  compute(1);

  const int crow0 = tm * BM + wm * WM;
  const int ccol0 = tn * BN + wn * WN;
  #pragma unroll
  for (int i = 0; i < FM; ++i)
    #pragma unroll
    for (int j = 0; j < FN; ++j)
      #pragma unroll
      for (int e = 0; e < 4; ++e) {
        int r = crow0 + i * 16 + kq * 4 + e;
        int c = ccol0 + j * 16 + l16;
        float v = acc[i][j][e];
        if (bias) v += bias[c];
        if (res1) v += res1[(size_t)r * ldc + c];
        if (res2) v += res2[(size_t)r * ldc + c];
        if (do_relu) v = fmaxf(v, 0.f);
        if (C)  C [(size_t)r * ldc + c] = v;
        if (Cb) Cb[(size_t)r * ldc + c] = __float2bfloat16(v);
        if (Ct) Ct[(size_t)c * ldct + r] = __float2bfloat16(v);
      }
}

// reduce partials + bias -> out0f (fp32), out0b (bf16), T = out0^T (bf16).
__global__ __launch_bounds__(256)
void reduce_t(const __hip_bfloat16* __restrict__ parts, const float* __restrict__ bias,
              float* __restrict__ out0f, __hip_bfloat16* __restrict__ out0b,
              __hip_bfloat16* __restrict__ T)
{
  __shared__ float tile[32][33];
  int bx = blockIdx.x * 32;          // col in DHID
  int by = blockIdx.y * 32;          // row in N_PROP
  // read phase: 8 col-groups x 32 rows; ushort4 (4 cols) per thread.
  int tc = (threadIdx.x & 7) * 4;
  int tr = threadIdx.x >> 3;
  {
    int r = by + tr, c0 = bx + tc;
    float4 bv = *(const float4*)(bias + c0);
    float s0 = bv.x, s1 = bv.y, s2 = bv.z, s3 = bv.w;
    for (int sl = 0; sl < 32; ++sl) {
      ushort4 u = *(const ushort4*)(parts + (size_t)sl * (N_PROP * DHID) +
                                    (size_t)r * DHID + c0);
      s0 += bf2f(u.x); s1 += bf2f(u.y); s2 += bf2f(u.z); s3 += bf2f(u.w);
    }
    float4 o = {s0, s1, s2, s3};
    *(float4*)(out0f + (size_t)r * DHID + c0) = o;
    ushort4 ob = {(unsigned short)f2bf(s0), (unsigned short)f2bf(s1),
                  (unsigned short)f2bf(s2), (unsigned short)f2bf(s3)};
    *(ushort4*)(out0b + (size_t)r * DHID + c0) = ob;
    tile[tr][tc] = s0; tile[tr][tc + 1] = s1;
    tile[tr][tc + 2] = s2; tile[tr][tc + 3] = s3;
  }
  __syncthreads();
  int tx = threadIdx.x & 31, ty = threadIdx.x >> 5;
  #pragma unroll
  for (int i = 0; i < 4; ++i)
    T[(size_t)(bx + ty + i * 8) * N_PROP + by + tx] =
        __float2bfloat16(tile[tx][ty + i * 8]);
}

// row softmax of logits[512][512] (fp32 in), bf16 probabilities out.
__global__ __launch_bounds__(256)
void softmax_rows(const float* __restrict__ x, __hip_bfloat16* __restrict__ p, float scale)
{
  int row = blockIdx.x;
  const float* q = x + (size_t)row * N_PROP;
  int tid = threadIdx.x;
  float a = q[tid] * scale;
  float b = q[tid + 256] * scale;
  float m = fmaxf(a, b);
  #pragma unroll
  for (int o = 32; o > 0; o >>= 1) m = fmaxf(m, __shfl_xor(m, o));
  __shared__ float sm[4], ss[4];
  int w = tid >> 6;
  if ((tid & 63) == 0) sm[w] = m;
  __syncthreads();
  m = fmaxf(fmaxf(sm[0], sm[1]), fmaxf(sm[2], sm[3]));
  float ea = __expf(a - m), eb = __expf(b - m);
  float s = ea + eb;
  #pragma unroll
  for (int o = 32; o > 0; o >>= 1) s += __shfl_xor(s, o);
  if ((tid & 63) == 0) ss[w] = s;
  __syncthreads();
  s = ss[0] + ss[1] + ss[2] + ss[3];
  float inv = 1.f / s;
  p[(size_t)row * N_PROP + tid]       = __float2bfloat16(ea * inv);
  p[(size_t)row * N_PROP + tid + 256] = __float2bfloat16(eb * inv);
}

extern "C" void kernel_launch(void* const* d_in, const int* in_sizes, int n_in,
                              void* d_out, int out_size, void* d_ws, size_t ws_size,
                              hipStream_t stream)
{
  (void)in_sizes; (void)n_in; (void)out_size; (void)ws_size;
  const float* x      = (const float*)d_in[0];
  const float* fc1_w  = (const float*)d_in[1];
  const float* fc1_b  = (const float*)d_in[2];
  const float* fc2_w  = (const float*)d_in[3];
  const float* fc2_b  = (const float*)d_in[4];
  const float* a1w1   = (const float*)d_in[5];
  const float* a1b1   = (const float*)d_in[6];
  const float* a1w2   = (const float*)d_in[7];
  const float* a1b2   = (const float*)d_in[8];
  const float* a1cw   = (const float*)d_in[9];
  const float* a1cb   = (const float*)d_in[10];
  const float* a2w1   = (const float*)d_in[11];
  const float* a2b1   = (const float*)d_in[12];
  const float* a2w2   = (const float*)d_in[13];
  const float* a2b2   = (const float*)d_in[14];
  const float* a2cw   = (const float*)d_in[15];
  const float* a2cb   = (const float*)d_in[16];
  float* out = (float*)d_out;

  typedef __hip_bfloat16 bf16;
  char* ws = (char*)d_ws;
  const size_t MB = 1024 * 1024;
  float* out0f  = (float*)(ws + 0 * MB);            // 2 MB
  float* h1f    = (float*)(ws + 2 * MB);            // 2 MB
  float* logits = (float*)(ws + 4 * MB);            // 1 MB
  bf16*  out0b  = (bf16*)(ws + 5 * MB);             // 1 MB
  bf16*  T      = (bf16*)(ws + 6 * MB);             // 1 MB (out0^T)
  bf16*  q      = (bf16*)(ws + 7 * MB);             // 1 MB
  bf16*  k      = (bf16*)(ws + 8 * MB);             // 1 MB (adjacent to q: dual-z)
  bf16*  att    = (bf16*)(ws + 9 * MB);             // 1 MB
  bf16*  h0b    = (bf16*)(ws + 10 * MB);            // 1 MB
  bf16*  h1b    = (bf16*)(ws + 11 * MB);            // 1 MB
  bf16*  T2     = (bf16*)(ws + 12 * MB);            // 1 MB (h1^T)
  bf16*  pb     = (bf16*)(ws + 13 * MB);            // 0.5 MB
  bf16*  parts  = (bf16*)(ws + 14 * MB);            // 32 MB
  const size_t ND = (size_t)N_PROP * DHID;
  dim3 blk(256);

  // ---- fc1 + fused reduce/bias/transpose ----
  gemm_fc1<<<dim3(256), dim3(1024), 0, stream>>>(x, fc1_w, parts);
  reduce_t<<<dim3(DHID / 32, N_PROP / 32), blk, 0, stream>>>(
      parts, fc1_b, out0f, out0b, T);

  // ---- attention 1 ----
  gemm_bf<32, 64, 128, float><<<dim3(256, 1, 2), blk, 0, stream>>>(
      out0b, DHID, a1w1, a1w2, DHID,
      nullptr, q, DHID, 16, DHID, ND,
      a1b1, a1b2, nullptr, nullptr, nullptr, 0, 0);
  gemm_bf<32, 32, 128, bf16><<<dim3(256), blk, 0, stream>>>(
      q, DHID, k, nullptr, DHID,
      logits, nullptr, N_PROP, 16, DHID, 0,
      nullptr, nullptr, nullptr, nullptr, nullptr, 0, 0);
  softmax_rows<<<N_PROP, blk, 0, stream>>>(logits, pb, SM_SCALE);
  gemm_bf<32, 64, 128, bf16><<<dim3(256), blk, 0, stream>>>(
      pb, N_PROP, T, nullptr, N_PROP,
      nullptr, att, DHID, 16, N_PROP, 0,
      nullptr, nullptr, nullptr, nullptr, nullptr, 0, 0);
  // h0 = relu(out0 + att @ a1cw^T + a1cb)
  gemm_bf<32, 64, 128, float><<<dim3(256), blk, 0, stream>>>(
      att, DHID, a1cw, nullptr, DHID,
      nullptr, h0b, DHID, 16, DHID, 0,
      a1cb, nullptr, out0f, nullptr, nullptr, 0, 1);
  // h1 = h0 @ fc2^T + fc2_b ; emit h1f + h1b + T2 = h1^T
  gemm_bf<32, 64, 128, float><<<dim3(256), blk, 0, stream>>>(
      h0b, DHID, fc2_w, nullptr, DHID,
      h1f, h1b, DHID, 16, DHID, 0,
      fc2_b, nullptr, nullptr, nullptr, T2, N_PROP, 0);

  // ---- attention 2 ----
  gemm_bf<32, 64, 128, float><<<dim3(256, 1, 2), blk, 0, stream>>>(
      h1b, DHID, a2w1, a2w2, DHID,
      nullptr, q, DHID, 16, DHID, ND,
      a2b1, a2b2, nullptr, nullptr, nullptr, 0, 0);
  gemm_bf<32, 32, 128, bf16><<<dim3(256), blk, 0, stream>>>(
      q, DHID, k, nullptr, DHID,
      logits, nullptr, N_PROP, 16, DHID, 0,
      nullptr, nullptr, nullptr, nullptr, nullptr, 0, 0);
  softmax_rows<<<N_PROP, blk, 0, stream>>>(logits, pb, SM_SCALE);
  gemm_bf<32, 64, 128, bf16><<<dim3(256), blk, 0, stream>>>(
      pb, N_PROP, T2, nullptr, N_PROP,
      nullptr, att, DHID, 16, N_PROP, 0,
      nullptr, nullptr, nullptr, nullptr, nullptr, 0, 0);
  // final = relu(h1 + att @ a2cw^T + a2cb + out0)
  gemm_bf<32, 64, 128, float><<<dim3(256), blk, 0, stream>>>(
      att, DHID, a2cw, nullptr, DHID,
      out, nullptr, DHID, 16, DHID, 0,
      a2cb, nullptr, h1f, out0f, nullptr, 0, 1);
}

// Round 12
// 185.550 us; speedup vs baseline: 4.4112x; 1.0570x over previous
//
#include <hip/hip_runtime.h>
#include <hip/hip_bf16.h>

typedef __attribute__((ext_vector_type(8))) short short8;
typedef __attribute__((ext_vector_type(4))) float f32x4;

#define N_PROP 512
#define DHID   1024
#define KFLAT  50176
#define SM_SCALE 0.03125f  /* 1/sqrt(1024) */

__device__ inline short f2bf(float x) {
  __hip_bfloat16 b = __float2bfloat16(x);
  return __builtin_bit_cast(short, b);
}
__device__ inline float bf2f(unsigned short u) {
  unsigned int x = (unsigned int)u << 16;
  return __builtin_bit_cast(float, x);
}

// Raw barrier WITHOUT the compiler's vmcnt(0) drain: lgkmcnt(0) orders LDS
// writes/reads across the barrier; global loads stay in flight.
__device__ inline void pinned_bar() {
  asm volatile("s_waitcnt lgkmcnt(0)" ::: "memory");
  __builtin_amdgcn_s_barrier();
  asm volatile("" ::: "memory");
}

// ---------------- fc1: round-8 kernel + NON-TEMPORAL B(weight) loads --------
// Theory: fc1 is bound at ~6.4 TB/s beyond-L2 delivery for 822 MB requested
// (A x4 + B x2). nt on the B stream keeps L2 free for the A k-window so the
// A re-reads (411 MB) become L2 hits -> beyond-L2 ~514 MB. Pure hint: the
// neutral case is byte-identical to round 8's 128 us.
// (nt builtin requires ext-vector pointers, not HIP_vector_type — use f32x4.)
__global__ __launch_bounds__(1024, 4)
void gemm_fc1(const float* __restrict__ A, const float* __restrict__ B,
              __hip_bfloat16* __restrict__ parts)
{
  constexpr int BK = 32;
  constexpr int KLEN = 1568, NT = KLEN / BK;   // 49
  __shared__ short sA[2][256 * 32];
  __shared__ short sB[2][256 * 32];            // 64 KB total

  const int n = gridDim.x;
  int lid = blockIdx.x;
  lid = (lid & 7) * (n >> 3) + (lid >> 3);
  const int y    = lid >> 3;
  const int tile = lid & 7;
  const int tm = tile >> 2;
  const int tn = tile & 3;

  const int k0 = y * KLEN;

  const int tid  = threadIdx.x;
  const int lane = tid & 63;
  const int wid  = tid >> 6;
  const int wr = wid >> 2, wc = wid & 3;
  const int l16 = lane & 15, kq = lane >> 4;

  const float* Ab = A + (size_t)(tm * 256) * KFLAT;
  const float* Bb = B + (size_t)(tn * 256) * KFLAT;

  const int srow = tid >> 2;
  const int sc   = tid & 3;
  const int sphys = sc ^ ((srow >> 1) & 3);

  f32x4 acc[4][4];
  #pragma unroll
  for (int i = 0; i < 4; ++i)
    #pragma unroll
    for (int j = 0; j < 4; ++j)
      acc[i][j] = (f32x4){0.f, 0.f, 0.f, 0.f};

  float4 ra0, ra1;
  f32x4  rb0, rb1;

  auto loadAB = [&](int kk) {
    const float* pa = Ab + (size_t)srow * KFLAT + kk + sc * 8;
    const float* pb = Bb + (size_t)srow * KFLAT + kk + sc * 8;
    ra0 = *(const float4*)pa; ra1 = *(const float4*)(pa + 4);
    rb0 = __builtin_nontemporal_load((const f32x4*)pb);       // nt: stream
    rb1 = __builtin_nontemporal_load((const f32x4*)pb + 1);   // nt: stream
  };
  auto storeAB = [&](int b) {
    short8 s;
    s[0]=f2bf(ra0.x); s[1]=f2bf(ra0.y); s[2]=f2bf(ra0.z); s[3]=f2bf(ra0.w);
    s[4]=f2bf(ra1.x); s[5]=f2bf(ra1.y); s[6]=f2bf(ra1.z); s[7]=f2bf(ra1.w);
    *(short8*)&sA[b][srow * 32 + sphys * 8] = s;
    s[0]=f2bf(rb0[0]); s[1]=f2bf(rb0[1]); s[2]=f2bf(rb0[2]); s[3]=f2bf(rb0[3]);
    s[4]=f2bf(rb1[0]); s[5]=f2bf(rb1[1]); s[6]=f2bf(rb1[2]); s[7]=f2bf(rb1[3]);
    *(short8*)&sB[b][srow * 32 + sphys * 8] = s;
  };
  auto compute = [&](int b) {
    short8 af[4], bf[4];
    #pragma unroll
    for (int i = 0; i < 4; ++i) {
      int R  = wr * 64 + i * 16 + l16;
      int ph = kq ^ ((R >> 1) & 3);
      af[i] = *(short8*)&sA[b][R * 32 + ph * 8];
    }
    #pragma unroll
    for (int j = 0; j < 4; ++j) {
      int R  = wc * 64 + j * 16 + l16;
      int ph = kq ^ ((R >> 1) & 3);
      bf[j] = *(short8*)&sB[b][R * 32 + ph * 8];
    }
    #pragma unroll
    for (int i = 0; i < 4; ++i)
      #pragma unroll
      for (int j = 0; j < 4; ++j)
        acc[i][j] = __builtin_amdgcn_mfma_f32_16x16x32_bf16(af[i], bf[j], acc[i][j], 0, 0, 0);
  };

  loadAB(k0);
  storeAB(0);
  loadAB(k0 + BK);
  pinned_bar();

  int cur = 0;
  for (int t = 0; t < NT; ++t) {
    if (t + 1 < NT) {
      storeAB(cur ^ 1);
      if (t + 2 < NT) loadAB(k0 + (t + 2) * BK);
    }
    compute(cur);
    pinned_bar();
    cur ^= 1;
  }

  __hip_bfloat16* P = parts + (size_t)y * (N_PROP * DHID);
  const int crow0 = tm * 256 + wr * 64;
  const int ccol0 = tn * 256 + wc * 64;
  #pragma unroll
  for (int i = 0; i < 4; ++i)
    #pragma unroll
    for (int j = 0; j < 4; ++j)
      #pragma unroll
      for (int e = 0; e < 4; ++e) {
        int r = crow0 + i * 16 + kq * 4 + e;
        int c = ccol0 + j * 16 + l16;
        P[(size_t)r * DHID + c] = __float2bfloat16(acc[i][j][e]);
      }
}

// ---------------- tail GEMM: bf16 A; B fp32 (weights) or bf16; triple-z -----
// Static register sets + unroll-2 (rule #20). Epilogue: +bias +res1 +res2,
// relu, write C (fp32) / Cb (bf16, z-strided) / Ct (bf16 transpose, only on
// blockIdx.z == ct_z).  nt (ktot/BK) must be even (8 or 4 here).
template<int BM, int BN, int BK, typename BT>
__global__ __launch_bounds__(256, 2)
void gemm_bf(const __hip_bfloat16* __restrict__ A, int lda,
             const BT* __restrict__ B1, const BT* __restrict__ B2,
             const BT* __restrict__ B3, int ldb,
             float* __restrict__ C, __hip_bfloat16* __restrict__ Cb, int ldc,
             int tiles_n, int ktot, size_t c_z_stride,
             const float* __restrict__ bias1, const float* __restrict__ bias2,
             const float* __restrict__ bias3,
             const float* __restrict__ res1, const float* __restrict__ res2,
             __hip_bfloat16* __restrict__ Ct, int ldct, int ct_z, int do_relu)
{
  constexpr int BKP = BK + 8;
  constexpr int WM = BM / 2, WN = BN / 2;
  constexpr int FM = WM / 16, FN = WN / 16;
  constexpr int NC = BK / 8;
  constexpr int NA = (BM * BK) / (8 * 256);
  constexpr int NB = (BN * BK) / (8 * 256);
  constexpr bool BF = sizeof(BT) == 2;

  __shared__ short As[2][BM * BKP];
  __shared__ short Bs[2][BN * BKP];

  const int n = gridDim.x;
  int lid = blockIdx.x;
  lid = (lid & 7) * (n >> 3) + (lid >> 3);
  const int tm = lid / tiles_n;
  const int tn = lid % tiles_n;
  const int nt = ktot / BK;

  if (C)  C  += (size_t)blockIdx.z * c_z_stride;
  if (Cb) Cb += (size_t)blockIdx.z * c_z_stride;
  const BT* B       = blockIdx.z == 0 ? B1 : (blockIdx.z == 1 ? B2 : B3);
  const float* bias = blockIdx.z == 0 ? bias1 : (blockIdx.z == 1 ? bias2 : bias3);
  const bool wr_ct  = Ct && ((int)blockIdx.z == ct_z);

  const int tid  = threadIdx.x;
  const int lane = tid & 63;
  const int wid  = tid >> 6;
  const int wm = wid >> 1, wn = wid & 1;
  const int l16 = lane & 15, kq = lane >> 4;

  const __hip_bfloat16* Ab = A + (size_t)(tm * BM) * lda;
  const BT*             Bb = B + (size_t)(tn * BN) * ldb;

  f32x4 acc[FM][FN];
  #pragma unroll
  for (int i = 0; i < FM; ++i)
    #pragma unroll
    for (int j = 0; j < FN; ++j)
      acc[i][j] = (f32x4){0.f, 0.f, 0.f, 0.f};

  // statically named staging sets (rule #20)
  short8 a0[NA]; short8 b0h[NB]; float4 b0f[NB][2];
  short8 a1[NA]; short8 b1h[NB]; float4 b1f[NB][2];

  auto load0 = [&](int kk) {
    #pragma unroll
    for (int i = 0; i < NA; ++i) {
      int ch = tid + i * 256; int r = ch / NC, c = (ch % NC) * 8;
      a0[i] = *(const short8*)(Ab + (size_t)r * lda + kk + c);
    }
    #pragma unroll
    for (int i = 0; i < NB; ++i) {
      int ch = tid + i * 256; int r = ch / NC, c = (ch % NC) * 8;
      if constexpr (BF) b0h[i] = *(const short8*)(Bb + (size_t)r * ldb + kk + c);
      else {
        const float* p = (const float*)Bb + (size_t)r * ldb + kk + c;
        b0f[i][0] = *(const float4*)p; b0f[i][1] = *(const float4*)(p + 4);
      }
    }
  };
  auto load1 = [&](int kk) {
    #pragma unroll
    for (int i = 0; i < NA; ++i) {
      int ch = tid + i * 256; int r = ch / NC, c = (ch % NC) * 8;
      a1[i] = *(const short8*)(Ab + (size_t)r * lda + kk + c);
    }
    #pragma unroll
    for (int i = 0; i < NB; ++i) {
      int ch = tid + i * 256; int r = ch / NC, c = (ch % NC) * 8;
      if constexpr (BF) b1h[i] = *(const short8*)(Bb + (size_t)r * ldb + kk + c);
      else {
        const float* p = (const float*)Bb + (size_t)r * ldb + kk + c;
        b1f[i][0] = *(const float4*)p; b1f[i][1] = *(const float4*)(p + 4);
      }
    }
  };
  auto store0 = [&](int buf) {
    #pragma unroll
    for (int i = 0; i < NA; ++i) {
      int ch = tid + i * 256; int r = ch / NC, c = (ch % NC) * 8;
      *(short8*)&As[buf][r * BKP + c] = a0[i];
    }
    #pragma unroll
    for (int i = 0; i < NB; ++i) {
      int ch = tid + i * 256; int r = ch / NC, c = (ch % NC) * 8;
      if constexpr (BF) *(short8*)&Bs[buf][r * BKP + c] = b0h[i];
      else {
        float4 u = b0f[i][0], v = b0f[i][1];
        short8 w;
        w[0]=f2bf(u.x); w[1]=f2bf(u.y); w[2]=f2bf(u.z); w[3]=f2bf(u.w);
        w[4]=f2bf(v.x); w[5]=f2bf(v.y); w[6]=f2bf(v.z); w[7]=f2bf(v.w);
        *(short8*)&Bs[buf][r * BKP + c] = w;
      }
    }
  };
  auto store1 = [&](int buf) {
    #pragma unroll
    for (int i = 0; i < NA; ++i) {
      int ch = tid + i * 256; int r = ch / NC, c = (ch % NC) * 8;
      *(short8*)&As[buf][r * BKP + c] = a1[i];
    }
    #pragma unroll
    for (int i = 0; i < NB; ++i) {
      int ch = tid + i * 256; int r = ch / NC, c = (ch % NC) * 8;
      if constexpr (BF) *(short8*)&Bs[buf][r * BKP + c] = b1h[i];
      else {
        float4 u = b1f[i][0], v = b1f[i][1];
        short8 w;
        w[0]=f2bf(u.x); w[1]=f2bf(u.y); w[2]=f2bf(u.z); w[3]=f2bf(u.w);
        w[4]=f2bf(v.x); w[5]=f2bf(v.y); w[6]=f2bf(v.z); w[7]=f2bf(v.w);
        *(short8*)&Bs[buf][r * BKP + c] = w;
      }
    }
  };
  auto compute = [&](int buf) {
    #pragma unroll
    for (int ks = 0; ks < BK / 32; ++ks) {
      short8 af[FM], bf[FN];
      #pragma unroll
      for (int i = 0; i < FM; ++i)
        af[i] = *(short8*)&As[buf][(wm * WM + i * 16 + l16) * BKP + ks * 32 + kq * 8];
      #pragma unroll
      for (int j = 0; j < FN; ++j)
        bf[j] = *(short8*)&Bs[buf][(wn * WN + j * 16 + l16) * BKP + ks * 32 + kq * 8];
      #pragma unroll
      for (int i = 0; i < FM; ++i)
        #pragma unroll
        for (int j = 0; j < FN; ++j)
          acc[i][j] = __builtin_amdgcn_mfma_f32_16x16x32_bf16(af[i], bf[j], acc[i][j], 0, 0, 0);
    }
  };

  load0(0);
  store0(0);
  load1(BK);
  pinned_bar();

  int t = 0;
  for (; t + 2 < nt; t += 2) {
    store1(1); load0((t + 2) * BK);
    compute(0); pinned_bar();
    store0(0); load1((t + 3) * BK);
    compute(1); pinned_bar();
  }
  store1(1);
  compute(0); pinned_bar();
  compute(1);

  const int crow0 = tm * BM + wm * WM;
  const int ccol0 = tn * BN + wn * WN;
  #pragma unroll
  for (int i = 0; i < FM; ++i)
    #pragma unroll
    for (int j = 0; j < FN; ++j)
      #pragma unroll
      for (int e = 0; e < 4; ++e) {
        int r = crow0 + i * 16 + kq * 4 + e;
        int c = ccol0 + j * 16 + l16;
        float v = acc[i][j][e];
        if (bias) v += bias[c];
        if (res1) v += res1[(size_t)r * ldc + c];
        if (res2) v += res2[(size_t)r * ldc + c];
        if (do_relu) v = fmaxf(v, 0.f);
        if (C)  C [(size_t)r * ldc + c] = v;
        if (Cb) Cb[(size_t)r * ldc + c] = __float2bfloat16(v);
        if (wr_ct) Ct[(size_t)c * ldct + r] = __float2bfloat16(v);
      }
}

// reduce 32 bf16 partial slices + bias -> out0f (fp32) + out0b (bf16).
__global__ __launch_bounds__(256)
void reduce_s(const __hip_bfloat16* __restrict__ parts, const float* __restrict__ bias,
              float* __restrict__ out0f, __hip_bfloat16* __restrict__ out0b)
{
  int idx4 = blockIdx.x * 256 + threadIdx.x;        // over ND/4
  int c4 = idx4 & (DHID / 4 - 1);
  float4 b = *(const float4*)(bias + (size_t)c4 * 4);
  float s0 = b.x, s1 = b.y, s2 = b.z, s3 = b.w;
  for (int i = 0; i < 32; ++i) {
    ushort4 u = *(const ushort4*)(parts + (size_t)i * (N_PROP * DHID) +
                                  (size_t)idx4 * 4);
    s0 += bf2f(u.x); s1 += bf2f(u.y); s2 += bf2f(u.z); s3 += bf2f(u.w);
  }
  float4 o = {s0, s1, s2, s3};
  *(float4*)(out0f + (size_t)idx4 * 4) = o;
  ushort4 ob = {(unsigned short)f2bf(s0), (unsigned short)f2bf(s1),
                (unsigned short)f2bf(s2), (unsigned short)f2bf(s3)};
  *(ushort4*)(out0b + (size_t)idx4 * 4) = ob;
}

// row softmax of logits[512][512] (fp32 in), bf16 probabilities out.
__global__ __launch_bounds__(256)
void softmax_rows(const float* __restrict__ x, __hip_bfloat16* __restrict__ p, float scale)
{
  int row = blockIdx.x;
  const float* q = x + (size_t)row * N_PROP;
  int tid = threadIdx.x;
  float a = q[tid] * scale;
  float b = q[tid + 256] * scale;
  float m = fmaxf(a, b);
  #pragma unroll
  for (int o = 32; o > 0; o >>= 1) m = fmaxf(m, __shfl_xor(m, o));
  __shared__ float sm[4], ss[4];
  int w = tid >> 6;
  if ((tid & 63) == 0) sm[w] = m;
  __syncthreads();
  m = fmaxf(fmaxf(sm[0], sm[1]), fmaxf(sm[2], sm[3]));
  float ea = __expf(a - m), eb = __expf(b - m);
  float s = ea + eb;
  #pragma unroll
  for (int o = 32; o > 0; o >>= 1) s += __shfl_xor(s, o);
  if ((tid & 63) == 0) ss[w] = s;
  __syncthreads();
  s = ss[0] + ss[1] + ss[2] + ss[3];
  float inv = 1.f / s;
  p[(size_t)row * N_PROP + tid]       = __float2bfloat16(ea * inv);
  p[(size_t)row * N_PROP + tid + 256] = __float2bfloat16(eb * inv);
}

extern "C" void kernel_launch(void* const* d_in, const int* in_sizes, int n_in,
                              void* d_out, int out_size, void* d_ws, size_t ws_size,
                              hipStream_t stream)
{
  (void)in_sizes; (void)n_in; (void)out_size; (void)ws_size;
  const float* x      = (const float*)d_in[0];
  const float* fc1_w  = (const float*)d_in[1];
  const float* fc1_b  = (const float*)d_in[2];
  const float* fc2_w  = (const float*)d_in[3];
  const float* fc2_b  = (const float*)d_in[4];
  const float* a1w1   = (const float*)d_in[5];
  const float* a1b1   = (const float*)d_in[6];
  const float* a1w2   = (const float*)d_in[7];
  const float* a1b2   = (const float*)d_in[8];
  const float* a1cw   = (const float*)d_in[9];
  const float* a1cb   = (const float*)d_in[10];
  const float* a2w1   = (const float*)d_in[11];
  const float* a2b1   = (const float*)d_in[12];
  const float* a2w2   = (const float*)d_in[13];
  const float* a2b2   = (const float*)d_in[14];
  const float* a2cw   = (const float*)d_in[15];
  const float* a2cb   = (const float*)d_in[16];
  float* out = (float*)d_out;

  typedef __hip_bfloat16 bf16;
  char* ws = (char*)d_ws;
  const size_t MB = 1024 * 1024;
  float* out0f  = (float*)(ws + 0 * MB);            // 2 MB
  float* h1f    = (float*)(ws + 2 * MB);            // 2 MB
  float* logits = (float*)(ws + 4 * MB);            // 1 MB
  bf16*  out0b  = (bf16*)(ws + 5 * MB);             // 1 MB
  bf16*  h0b    = (bf16*)(ws + 6 * MB);             // 1 MB
  bf16*  q      = (bf16*)(ws + 7 * MB);             // 1 MB  (z=0)
  bf16*  k      = (bf16*)(ws + 8 * MB);             // 1 MB  (z=1, q+ND)
  // ws + 9 MB: V' non-transposed (z=2, written but unused)
  bf16*  Vt     = (bf16*)(ws + 10 * MB);            // 1 MB  (V'^T, 1024x512)
  bf16*  h1b    = (bf16*)(ws + 11 * MB);            // 1 MB
  bf16*  pb     = (bf16*)(ws + 12 * MB);            // 0.5 MB
  bf16*  parts  = (bf16*)(ws + 13 * MB);            // 32 MB -> 45 MB total
  const size_t ND = (size_t)N_PROP * DHID;
  dim3 blk(256);

  // ---- fc1 (nt-B) + reduce ----
  gemm_fc1<<<dim3(256), dim3(1024), 0, stream>>>(x, fc1_w, parts);
  reduce_s<<<dim3(512), blk, 0, stream>>>(parts, fc1_b, out0f, out0b);

  // ---- attention 1:  q | k | V' = out0@a1cw^T + a1cb  (V'^T side-written) --
  gemm_bf<32, 64, 128, float><<<dim3(256, 1, 3), blk, 0, stream>>>(
      out0b, DHID, a1w1, a1w2, a1cw, DHID,
      nullptr, q, DHID, 16, DHID, ND,
      a1b1, a1b2, a1cb, nullptr, nullptr, Vt, N_PROP, 2, 0);
  gemm_bf<32, 32, 128, bf16><<<dim3(256), blk, 0, stream>>>(
      q, DHID, k, nullptr, nullptr, DHID,
      logits, nullptr, N_PROP, 16, DHID, 0,
      nullptr, nullptr, nullptr, nullptr, nullptr, nullptr, 0, -1, 0);
  softmax_rows<<<N_PROP, blk, 0, stream>>>(logits, pb, SM_SCALE);
  // h0 = relu(out0 + P @ V')   [= relu(out0 + (P@out0)@cw^T + cb)]
  gemm_bf<32, 64, 128, bf16><<<dim3(256), blk, 0, stream>>>(
      pb, N_PROP, Vt, nullptr, nullptr, N_PROP,
      nullptr, h0b, DHID, 16, N_PROP, 0,
      nullptr, nullptr, nullptr, out0f, nullptr, nullptr, 0, -1, 1);
  // h1 = h0 @ fc2^T + fc2_b  (fp32 + bf16 copies)
  gemm_bf<32, 64, 128, float><<<dim3(256), blk, 0, stream>>>(
      h0b, DHID, fc2_w, nullptr, nullptr, DHID,
      h1f, h1b, DHID, 16, DHID, 0,
      fc2_b, nullptr, nullptr, nullptr, nullptr, nullptr, 0, -1, 0);

  // ---- attention 2 ----
  gemm_bf<32, 64, 128, float><<<dim3(256, 1, 3), blk, 0, stream>>>(
      h1b, DHID, a2w1, a2w2, a2cw, DHID,
      nullptr, q, DHID, 16, DHID, ND,
      a2b1, a2b2, a2cb, nullptr, nullptr, Vt, N_PROP, 2, 0);
  gemm_bf<32, 32, 128, bf16><<<dim3(256), blk, 0, stream>>>(
      q, DHID, k, nullptr, nullptr, DHID,
      logits, nullptr, N_PROP, 16, DHID, 0,
      nullptr, nullptr, nullptr, nullptr, nullptr, nullptr, 0, -1, 0);
  softmax_rows<<<N_PROP, blk, 0, stream>>>(logits, pb, SM_SCALE);
  // out = relu(h1 + P @ V2' + out0)
  gemm_bf<32, 64, 128, bf16><<<dim3(256), blk, 0, stream>>>(
      pb, N_PROP, Vt, nullptr, nullptr, N_PROP,
      out, nullptr, DHID, 16, N_PROP, 0,
      nullptr, nullptr, nullptr, h1f, out0f, nullptr, 0, -1, 1);
}